// Round 4
// baseline (315.984 us; speedup 1.0000x reference)
//
#include <hip/hip_runtime.h>
#include <stdint.h>

#pragma clang fp contract(off)

#define BB 16
#define NN 25200
#define CCH 85
#define KTOP 512
#define NBKT 1024
#define CAP 1024

// ws layout: conf float[BB*NN] @ 0 (1,612,800 bytes). Nothing else.

__global__ __launch_bounds__(256) void k_conf(const float* __restrict__ x,
                                              float* __restrict__ conf) {
    __shared__ float tile[128 * CCH];
    const int blk = blockIdx.x;
    const int tid = threadIdx.x;

    const float4* src = (const float4*)x + (size_t)blk * 2720;
    float4* dst = (float4*)tile;
    for (int i = tid; i < 2720; i += 256) dst[i] = src[i];
    __syncthreads();

    const int r = tid >> 1;
    const int half = tid & 1;
    const float* row = tile + r * CCH;
    const float obj = row[4];

    float best = -1.0f;
    const float* cp = row + 5 + half * 40;
#pragma unroll
    for (int j = 0; j < 40; ++j) best = fmaxf(best, cp[j] * obj);
    best = fmaxf(best, __shfl_xor(best, 1));

    if (half == 0) {
        const int gr = blk * 128 + r;
        conf[gr] = ((obj > 0.01f) && (best > 0.01f)) ? best : -1.0f;
    }
}

__global__ __launch_bounds__(1024) void k_fused(const float* __restrict__ x,
                                                const float* __restrict__ target,
                                                const float* __restrict__ conf,
                                                float* __restrict__ out) {
    __shared__ union {
        unsigned hist[NBKT];               // phase A (4 KB)
        unsigned mask[KTOP][16];           // phases E/F (32 KB)
    } um;
    __shared__ unsigned long long cand[CAP];   // 8 KB
    __shared__ float4 sox[KTOP];               // 8 KB offset boxes
    __shared__ float sscore[KTOP];             // 2 KB
    __shared__ unsigned keep_words[16];
    __shared__ unsigned long long wred[16];
    __shared__ int sh_tstar, sh_cnt;

    const int b = blockIdx.x;
    const int tid = threadIdx.x;
    const int lane = tid & 63;
    const float4* cb4 = (const float4*)(conf + (size_t)b * NN);

    // ---- A: per-batch histogram (float4 loads) ----
    um.hist[tid] = 0u;
    if (tid == 0) { sh_tstar = 0; sh_cnt = 0; }
    __syncthreads();
    for (int i4 = tid; i4 < NN / 4; i4 += 1024) {
        float4 c4 = cb4[i4];
        float cs[4] = {c4.x, c4.y, c4.z, c4.w};
#pragma unroll
        for (int e = 0; e < 4; ++e) {
            float c = cs[e];
            if (c > 0.0f) {
                int bk = (int)(c * 1024.0f);
                if (bk > NBKT - 1) bk = NBKT - 1;
                atomicAdd(&um.hist[bk], 1u);
            }
        }
    }
    __syncthreads();

    // suffix-scan -> threshold bucket
    for (int off = 1; off < NBKT; off <<= 1) {
        unsigned v = um.hist[tid];
        if (tid + off < NBKT) v += um.hist[tid + off];
        __syncthreads();
        um.hist[tid] = v;
        __syncthreads();
    }
    if (um.hist[tid] >= KTOP && (tid == NBKT - 1 || um.hist[tid + 1] < KTOP)) sh_tstar = tid;
    __syncthreads();
    const int tstar = sh_tstar;

    // ---- B: gather candidates, wave-aggregated append ----
    for (int i4 = tid; i4 < NN / 4; i4 += 1024) {
        float4 c4 = cb4[i4];
        float cs[4] = {c4.x, c4.y, c4.z, c4.w};
#pragma unroll
        for (int e = 0; e < 4; ++e) {
            float c = cs[e];
            bool want = false;
            if (c > 0.0f) {
                int bk = (int)(c * 1024.0f);
                if (bk > NBKT - 1) bk = NBKT - 1;
                want = (bk >= tstar);
            }
            unsigned long long bal = __ballot(want);
            int base = 0;
            if (lane == 0 && bal) base = atomicAdd(&sh_cnt, __popcll(bal));
            base = __shfl(base, 0);
            if (want) {
                int pos = base + __popcll(bal & ((1ull << lane) - 1ull));
                if (pos < CAP) {
                    unsigned bits = __float_as_uint(c);
                    cand[pos] = ((unsigned long long)bits << 32) | (unsigned)(~(i4 * 4 + e));
                }
            }
        }
    }
    __syncthreads();
    const int M = min(sh_cnt, CAP);

    // ---- C: hybrid bitonic sort, descending ----
    unsigned long long key = (tid < M) ? cand[tid] : 0ull;
    __syncthreads();
    for (int kk = 2; kk <= CAP; kk <<= 1) {
        for (int j = kk >> 1; j > 0; j >>= 1) {
            unsigned long long partner;
            if (j >= 64) {
                cand[tid] = key;
                __syncthreads();
                partner = cand[tid ^ j];
                __syncthreads();
            } else {
                partner = __shfl_xor(key, j);
            }
            bool desc = (tid & kk) == 0;
            bool lower = (tid & j) == 0;
            bool take_max = (lower == desc);
            bool pg = partner > key;
            key = (take_max == pg) ? partner : key;
        }
    }
    cand[tid] = key;
    __syncthreads();

    // ---- D: 2 threads/row: box + class argmax recompute for top-512 ----
    const int rank = tid >> 1;
    const int half = tid & 1;
    unsigned long long rkey = cand[rank];
    float sc = __uint_as_float((unsigned)(rkey >> 32));
    unsigned idx = ~((unsigned)rkey);
    const bool v = sc > 0.0f;
    float X1 = 0.f, Y1 = 0.f, X2 = 0.f, Y2 = 0.f;
    int cl = 0;
    if (v) {
        const float* rw = x + ((size_t)b * NN + idx) * CCH;
        const float obj = rw[4];
        float bbest = -1.0f;
        int bi = 0;
        const float* cp = rw + 5 + half * 40;
#pragma unroll 8
        for (int j = 0; j < 40; ++j) {
            float p = cp[j] * obj;               // same rounded product as reference
            if (p > bbest) { bbest = p; bi = j; }
        }
        bi += half * 40;
        float ov = __shfl_xor(bbest, 1);
        int oi = __shfl_xor(bi, 1);
        if (half == 0) {
            if (ov > bbest) { bbest = ov; bi = oi; }   // tie -> lower class idx
            cl = bi;
            float cx = rw[0], cy = rw[1];
            float w = rw[2] * 0.5f, h = rw[3] * 0.5f;
            X1 = cx - w; Y1 = cy - h; X2 = cx + w; Y2 = cy + h;
        }
    }
    if (half == 0) {
        sscore[rank] = sc;
        float offv = (float)cl * 4096.0f;
        sox[rank] = make_float4(X1 + offv, Y1 + offv, X2 + offv, Y2 + offv);
    }
    __syncthreads();

    // ---- E: transposed suppression mask in LDS (lower triangle only) ----
    for (int p = tid; p < KTOP * 16; p += 1024) {
        int i = p & (KTOP - 1);
        int w = p >> 9;
        unsigned bits = 0u;
        if ((w << 5) < i) {
            float4 bi4 = sox[i];
            float ai = (bi4.z - bi4.x) * (bi4.w - bi4.y);
            const int jbase = w << 5;
            for (int jj = 0; jj < 32; ++jj) {
                int j = jbase + jj;
                float4 bj = sox[j];
                float lx = fmaxf(bi4.x, bj.x);
                float ly = fmaxf(bi4.y, bj.y);
                float rx = fminf(bi4.z, bj.z);
                float ry = fminf(bi4.w, bj.w);
                float inter = fmaxf(rx - lx, 0.0f) * fmaxf(ry - ly, 0.0f);
                float aj = (bj.z - bj.x) * (bj.w - bj.y);
                float den = ai + aj - inter + 1e-9f;
                float iou = inter / den;
                unsigned hit = (unsigned)((j < i) & (iou > 0.5f));
                bits |= hit << jj;
            }
        }
        um.mask[i][w] = bits;
    }
    __syncthreads();

    // ---- F: greedy scan on wave 0, mask-row prefetched ----
    if (tid < 64) {
        const int l15 = tid & 15;
        unsigned keepw = 0u;
        unsigned r_cur = um.mask[0][l15];
        float sc_cur = sscore[0];
        for (int i = 0; i < KTOP; ++i) {
            unsigned r_next = 0u; float sc_next = 0.f;
            if (i < KTOP - 1) { r_next = um.mask[i + 1][l15]; sc_next = sscore[i + 1]; }
            unsigned long long bal = __ballot((r_cur & keepw) != 0u);
            bool sup = (bal & 0xFFFFull) != 0ull;
            bool kept = (sc_cur > 0.0f) && !sup;
            if (kept && tid == (i >> 5)) keepw |= (1u << (i & 31));
            r_cur = r_next; sc_cur = sc_next;
        }
        if (tid < 16) keep_words[tid] = keepw;
    }
    __syncthreads();

    // ---- G: masked argmax of IoU-with-target, output ----
    const float tb0 = target[0], tb1 = target[1], tb2 = target[2], tb3 = target[3];
    const int tcls = (int)target[5];
    float m = -1.0f;
    if (half == 0) {
        bool kept = (keep_words[rank >> 5] >> (rank & 31)) & 1u;
        if (kept && cl == tcls) {
            float lx = fmaxf(X1, tb0);
            float ly = fmaxf(Y1, tb1);
            float rx = fminf(X2, tb2);
            float ry = fminf(Y2, tb3);
            float inter = fmaxf(rx - lx, 0.0f) * fmaxf(ry - ly, 0.0f);
            float areab = (X2 - X1) * (Y2 - Y1);
            float areat = (tb2 - tb0) * (tb3 - tb1);
            float den = areab + areat - inter + 1e-9f;
            m = inter / den;
        }
    }
    unsigned mb = __float_as_uint(m);
    unsigned mono = (mb & 0x80000000u) ? ~mb : (mb | 0x80000000u);
    unsigned long long rk = ((unsigned long long)mono << 32) | (unsigned)(~rank);
    for (int d = 32; d > 0; d >>= 1) {
        unsigned long long o = __shfl_xor(rk, d);
        if (o > rk) rk = o;
    }
    if ((tid & 63) == 0) wred[tid >> 6] = rk;
    __syncthreads();
    if (tid == 0) {
        unsigned long long bestk = wred[0];
        for (int i = 1; i < 16; ++i)
            if (wred[i] > bestk) bestk = wred[i];
        unsigned mono2 = (unsigned)(bestk >> 32);
        unsigned mbits = (mono2 & 0x80000000u) ? (mono2 & 0x7FFFFFFFu) : ~mono2;
        float mstar = __uint_as_float(mbits);
        int j = (int)(~((unsigned)bestk));
        out[b] = (mstar >= 0.0f) ? sscore[j] * mstar : 0.0f;
    }
}

extern "C" void kernel_launch(void* const* d_in, const int* in_sizes, int n_in,
                              void* d_out, int out_size, void* d_ws, size_t ws_size,
                              hipStream_t stream) {
    const float* x = (const float*)d_in[0];
    const float* target = (const float*)d_in[1];
    float* out = (float*)d_out;
    float* conf = (float*)d_ws;

    k_conf<<<dim3((BB * NN) / 128), dim3(256), 0, stream>>>(x, conf);
    k_fused<<<dim3(BB), dim3(1024), 0, stream>>>(x, target, conf, out);
}